// Round 1
// baseline (885.953 us; speedup 1.0000x reference)
//
#include <hip/hip_runtime.h>
#include <stdint.h>

typedef unsigned short u16;
typedef uint32_t u32;
typedef _Float16 f16x8 __attribute__((ext_vector_type(8)));
typedef u16 u16x8 __attribute__((ext_vector_type(8)));
typedef float f32x4 __attribute__((ext_vector_type(4)));

#define MFMA(a,b,c) __builtin_amdgcn_mfma_f32_16x16x32_f16((a),(b),(c),0,0,0)

constexpr int SN = 512;          // sequence N
constexpr int CC = 128;          // channels (CZ == CI)
constexpr int PP = SN * SN;      // positions
constexpr float LNEPS = 1e-5f;
constexpr float LO_SCALE = 2048.0f;     // 2^11: keeps residuals normal in fp16
constexpr float LO_INV   = 1.0f / 2048.0f;

// RNE bf16 quantization of an fp32 value (matches the np reference's input
// quantization — confirmed by an earlier first-validation pass).
__device__ __forceinline__ float bq(float f){
    u32 u = __builtin_bit_cast(u32, f);
    u += 0x7fffu + ((u >> 16) & 1u);
    return __builtin_bit_cast(float, u & 0xffff0000u);
}

// split fp32 -> (hi, lo) fp16 pair; x ~= hi + lo*2^-11, input precision ~2^-22
__device__ __forceinline__ void split2(float x, u16& h, u16& l){
    _Float16 a = (_Float16)x;
    _Float16 b = (_Float16)((x - (float)a) * LO_SCALE);
    h = __builtin_bit_cast(u16, a);
    l = __builtin_bit_cast(u16, b);
}
__device__ __forceinline__ u16 f2h(float f){
    _Float16 h = (_Float16)f;
    return __builtin_bit_cast(u16, h);
}
__device__ __forceinline__ f16x8 ld_frag(const u16* p){
    return __builtin_bit_cast(f16x8, *(const u16x8*)p);
}
__device__ __forceinline__ float sigm(float x){ return 1.0f / (1.0f + __expf(-x)); }

// Load 64 rows x 128 cols fp32 weights (row stride 128) -> bf16-quantized,
// split fp16 LDS, stride 136
__device__ __forceinline__ void load_w64s(const float* __restrict__ src,
                                          u16* dh, u16* dl, int tid){
    const int r = tid >> 2, q = tid & 3;
    const float4* s4 = (const float4*)(src + (size_t)r * CC + q * 32);
    u16* ph = dh + r * 136 + q * 32;
    u16* pl = dl + r * 136 + q * 32;
    #pragma unroll
    for (int j = 0; j < 8; ++j){
        float4 v = s4[j];
        split2(bq(v.x), ph[j*4+0], pl[j*4+0]);
        split2(bq(v.y), ph[j*4+1], pl[j*4+1]);
        split2(bq(v.z), ph[j*4+2], pl[j*4+2]);
        split2(bq(v.w), ph[j*4+3], pl[j*4+3]);
    }
}

// LayerNorm of 64 positions of act (bf16-quantized) -> split fp16 LDS [pos][c]
__device__ __forceinline__ void ln_split(const float* __restrict__ act, int p0,
        const float* __restrict__ lnw, const float* __restrict__ lnb,
        u16* sLh, u16* sLl, int tid){
    const int pos = tid >> 2, q = tid & 3;
    const float4* a4 = (const float4*)(act + (size_t)(p0 + pos) * CC + q * 32);
    float4 av[8];
    float s = 0.f, s2 = 0.f;
    #pragma unroll
    for (int j = 0; j < 8; ++j){
        av[j] = a4[j];
        av[j].x = bq(av[j].x); av[j].y = bq(av[j].y);
        av[j].z = bq(av[j].z); av[j].w = bq(av[j].w);
        s  += av[j].x + av[j].y + av[j].z + av[j].w;
        s2 += av[j].x*av[j].x + av[j].y*av[j].y + av[j].z*av[j].z + av[j].w*av[j].w;
    }
    s  += __shfl_xor(s, 1);  s  += __shfl_xor(s, 2);
    s2 += __shfl_xor(s2, 1); s2 += __shfl_xor(s2, 2);
    const float mean = s * (1.f / CC);
    const float rstd = rsqrtf(s2 * (1.f / CC) - mean * mean + LNEPS);
    const float4* w4 = (const float4*)(lnw + q * 32);
    const float4* b4 = (const float4*)(lnb + q * 32);
    u16* ph = sLh + pos * 136 + q * 32;
    u16* pl = sLl + pos * 136 + q * 32;
    #pragma unroll
    for (int j = 0; j < 8; ++j){
        float4 w = w4[j], b = b4[j];
        split2((av[j].x - mean) * rstd * bq(w.x) + bq(b.x), ph[j*4+0], pl[j*4+0]);
        split2((av[j].y - mean) * rstd * bq(w.y) + bq(b.y), ph[j*4+1], pl[j*4+1]);
        split2((av[j].z - mean) * rstd * bq(w.z) + bq(b.z), ph[j*4+2], pl[j*4+2]);
        split2((av[j].w - mean) * rstd * bq(w.w) + bq(b.w), ph[j*4+3], pl[j*4+3]);
    }
}

// 64x64 split-precision GEMM tile: res[t] (t<4 col-tiles) for this wave's 16 rows
__device__ __forceinline__ void gemm64s(const u16* sLh, const u16* sLl,
        const u16* sWh, const u16* sWl, int wave, int lq, int lr, f32x4* res){
    f32x4 ah[4], al[4];
    #pragma unroll
    for (int t = 0; t < 4; ++t){ ah[t] = f32x4{0,0,0,0}; al[t] = f32x4{0,0,0,0}; }
    #pragma unroll
    for (int kk = 0; kk < 4; ++kk){
        const int ao = (wave*16 + lr) * 136 + kk * 32 + lq * 8;
        const f16x8 a_h = ld_frag(sLh + ao);
        const f16x8 a_l = ld_frag(sLl + ao);
        #pragma unroll
        for (int t = 0; t < 4; ++t){
            const int bo = (t*16 + lr) * 136 + kk * 32 + lq * 8;
            const f16x8 b_h = ld_frag(sWh + bo);
            const f16x8 b_l = ld_frag(sWl + bo);
            ah[t] = MFMA(a_h, b_h, ah[t]);
            al[t] = MFMA(a_h, b_l, al[t]);
            al[t] = MFMA(a_l, b_h, al[t]);
        }
    }
    #pragma unroll
    for (int t = 0; t < 4; ++t) res[t] = ah[t] + al[t] * LO_INV;
}

// ---------------------------------------------------------------------------
// Kernel 1: LN + gate/proj (split-precision MFMA) -> lp/rp SPLIT fp16 (hi+lo),
// (c,i,k) layout. rpl may be null (then rp is stored hi-only).
// ---------------------------------------------------------------------------
__global__ __launch_bounds__(256) void k1_ln_proj(
        const float* __restrict__ act,  const float* __restrict__ mask,
        const float* __restrict__ lnw,  const float* __restrict__ lnb,
        const float* __restrict__ projw,const float* __restrict__ projb,
        const float* __restrict__ gatew,const float* __restrict__ gateb,
        u16* __restrict__ lph, u16* __restrict__ lpl,
        u16* __restrict__ rph, u16* __restrict__ rpl)
{
    __shared__ __align__(16) u16 sLh[64*136], sLl[64*136];
    __shared__ __align__(16) u16 sW[2*64*136];   // weight hi|lo; reused as fp16 stage tile
    u16* sWh = sW;
    u16* sWl = sW + 64*136;

    const int tid  = threadIdx.x;
    const int p0   = blockIdx.x * 64;
    const int irow = p0 >> 9;
    const int k0   = p0 & 511;

    ln_split(act, p0, lnw, lnb, sLh, sLl, tid);

    const int wave = tid >> 6, lane = tid & 63, lq = lane >> 4, lr = lane & 15;
    const float4 mv = *(const float4*)(mask + p0 + wave*16 + lq*4);
    const float mr[4] = {bq(mv.x), bq(mv.y), bq(mv.z), bq(mv.w)};

    #pragma unroll 1
    for (int gh = 0; gh < 4; ++gh){
        const int g = gh >> 1, h = gh & 1;
        const int cb = g * 128 + h * 64;

        __syncthreads();                            // sT reads done; publishes sL on gh=0
        load_w64s(gatew + (size_t)cb * CC, sWh, sWl, tid);
        __syncthreads();
        f32x4 gres[4]; gemm64s(sLh, sLl, sWh, sWl, wave, lq, lr, gres);
        __syncthreads();                            // gate-weight reads done
        load_w64s(projw + (size_t)cb * CC, sWh, sWl, tid);
        __syncthreads();
        f32x4 pres[4]; gemm64s(sLh, sLl, sWh, sWl, wave, lq, lr, pres);
        __syncthreads();                            // proj-weight reads done

        u16* sTh = sW;                              // 64x72 fp16 hi [col][pos]
        u16* sTl = sW + 64*72;                      // 64x72 fp16 lo [col][pos]
        #pragma unroll
        for (int t = 0; t < 4; ++t){
            const int col = t * 16 + lr;
            const float qb = bq(gateb[cb + col]);
            const float pb = bq(projb[cb + col]);
            #pragma unroll
            for (int r = 0; r < 4; ++r){
                const int pos = wave * 16 + lq * 4 + r;
                const float v = mr[r] * (pres[t][r] + pb) * sigm(gres[t][r] + qb);
                split2(v, sTh[col * 72 + pos], sTl[col * 72 + pos]);
            }
        }
        __syncthreads();

        {   // cooperative transposed write: dst[c][i][k] contiguous along k
            const int cl = tid >> 2, q = tid & 3;
            const size_t off = (size_t)(h*64 + cl) * PP + (size_t)irow * SN + k0 + q * 16;
            u16* dh = (g ? rph : lph) + off;
            const u16* sh = sTh + cl * 72 + q * 16;
            ((uint4*)dh)[0] = ((const uint4*)sh)[0];
            ((uint4*)dh)[1] = ((const uint4*)sh)[1];
            u16* lob = g ? rpl : lpl;
            if (lob){
                u16* dl = lob + off;
                const u16* sl = sTl + cl * 72 + q * 16;
                ((uint4*)dl)[0] = ((const uint4*)sl)[0];
                ((uint4*)dl)[1] = ((const uint4*)sl)[1];
            }
        }
    }
}

// ---------------------------------------------------------------------------
// Kernel 2: outT[c][i][j] = sum_k lp[c][i][k]*rp[c][j][k], split-precision
// fp16 MFMA (hi*hi + hi*lo + lo*hi; lo*lo ~2^-22 dropped), fp32 acc.
// RPS: rp has a lo plane. OT16: outT stored as fp16 instead of fp32.
// ---------------------------------------------------------------------------
template<int RPS, int OT16>
__global__ __launch_bounds__(256) void k2_einsum(
        const u16* __restrict__ lph, const u16* __restrict__ lpl,
        const u16* __restrict__ rph, const u16* __restrict__ rpl,
        void* __restrict__ outTv)
{
    __shared__ __align__(16) u16 sAh[128*72], sAl[128*72], sBh[128*72];
    __shared__ __align__(16) u16 sBl[RPS ? 128*72 : 8];
    const int tid = threadIdx.x;
    const int c   = blockIdx.z;
    const int i0  = blockIdx.y * 128;
    const int j0  = blockIdx.x * 128;
    const size_t aoff = (size_t)c * PP + (size_t)i0 * SN;
    const size_t boff = (size_t)c * PP + (size_t)j0 * SN;
    const int wave = tid >> 6, lane = tid & 63, lq = lane >> 4, lr = lane & 15;
    const int wi = (wave & 1) * 64, wj = (wave >> 1) * 64;
    const int row = tid >> 1, half = tid & 1;
    const size_t goff = (size_t)row * SN + half * 32;

    f32x4 acch[4][4], accl[4][4];
    #pragma unroll
    for (int m = 0; m < 4; ++m)
        #pragma unroll
        for (int n = 0; n < 4; ++n){ acch[m][n] = f32x4{0,0,0,0}; accl[m][n] = f32x4{0,0,0,0}; }

    for (int k0 = 0; k0 < SN; k0 += 64){
        const uint4* gah = (const uint4*)(lph + aoff + goff + k0);
        const uint4* gal = (const uint4*)(lpl + aoff + goff + k0);
        const uint4* gbh = (const uint4*)(rph + boff + goff + k0);
        uint4 Ah0 = gah[0], Ah1 = gah[1], Ah2 = gah[2], Ah3 = gah[3];
        uint4 Al0 = gal[0], Al1 = gal[1], Al2 = gal[2], Al3 = gal[3];
        uint4 Bh0 = gbh[0], Bh1 = gbh[1], Bh2 = gbh[2], Bh3 = gbh[3];
        uint4 Bl0, Bl1, Bl2, Bl3;
        if (RPS){
            const uint4* gbl = (const uint4*)(rpl + boff + goff + k0);
            Bl0 = gbl[0]; Bl1 = gbl[1]; Bl2 = gbl[2]; Bl3 = gbl[3];
        }
        __syncthreads();                          // prev iter's frag reads done
        uint4* dah = (uint4*)(sAh + row * 72 + half * 32);
        uint4* dal = (uint4*)(sAl + row * 72 + half * 32);
        uint4* dbh = (uint4*)(sBh + row * 72 + half * 32);
        dah[0] = Ah0; dah[1] = Ah1; dah[2] = Ah2; dah[3] = Ah3;
        dal[0] = Al0; dal[1] = Al1; dal[2] = Al2; dal[3] = Al3;
        dbh[0] = Bh0; dbh[1] = Bh1; dbh[2] = Bh2; dbh[3] = Bh3;
        if (RPS){
            uint4* dbl = (uint4*)(sBl + row * 72 + half * 32);
            dbl[0] = Bl0; dbl[1] = Bl1; dbl[2] = Bl2; dbl[3] = Bl3;
        }
        __syncthreads();
        #pragma unroll
        for (int kk = 0; kk < 64; kk += 32){
            f16x8 ahf[4], alf[4], bhf[4], blf[RPS ? 4 : 1];
            #pragma unroll
            for (int m = 0; m < 4; ++m){
                const int ro = (wi + m*16 + lr) * 72 + kk + lq * 8;
                ahf[m] = ld_frag(sAh + ro);
                alf[m] = ld_frag(sAl + ro);
            }
            #pragma unroll
            for (int n = 0; n < 4; ++n){
                const int ro = (wj + n*16 + lr) * 72 + kk + lq * 8;
                bhf[n] = ld_frag(sBh + ro);
                if (RPS) blf[n] = ld_frag(sBl + ro);
            }
            #pragma unroll
            for (int m = 0; m < 4; ++m)
                #pragma unroll
                for (int n = 0; n < 4; ++n){
                    acch[m][n] = MFMA(ahf[m], bhf[n], acch[m][n]);
                    accl[m][n] = MFMA(alf[m], bhf[n], accl[m][n]);
                    if (RPS) accl[m][n] = MFMA(ahf[m], blf[n], accl[m][n]);
                }
        }
    }
    #pragma unroll
    for (int m = 0; m < 4; ++m){
        const int ir = i0 + wi + m * 16 + lq * 4;
        #pragma unroll
        for (int n = 0; n < 4; ++n){
            const int jc = j0 + wj + n * 16 + lr;
            #pragma unroll
            for (int r = 0; r < 4; ++r){
                const float v = acch[m][n][r] + accl[m][n][r] * LO_INV;
                if (OT16)
                    ((u16*)outTv)[(size_t)c * PP + (size_t)(ir + r) * SN + jc] = f2h(v);
                else
                    ((float*)outTv)[(size_t)c * PP + (size_t)(ir + r) * SN + jc] = v;
            }
        }
    }
}

// ---------------------------------------------------------------------------
// Kernel 3: gate = sigmoid(LN(act)@glw.T+glb) recomputed; channel-LN of outT;
// final = (LN_c(outT) @ outpw.T + outpb) * gate -> d_out (write-only, once).
// ---------------------------------------------------------------------------
template<int OT16>
__global__ __launch_bounds__(256) void k3_out(
        const float* __restrict__ act,  const void* __restrict__ outTv,
        const float* __restrict__ lnw,  const float* __restrict__ lnb,
        const float* __restrict__ glw,  const float* __restrict__ glb,
        const float* __restrict__ cnw,  const float* __restrict__ cnb,
        const float* __restrict__ outpw,const float* __restrict__ outpb,
        float* __restrict__ io)
{
    // regionA (36864 B): phase1 sL pair | phase2 sRaw | phase2 outp-weight pair
    // regionB (34816 B): phase1 gl-weight pair | phase2 sLn pair
    __shared__ __align__(16) char smem[36864 + 34816];
    __shared__ float sRed[64 * 8];
    __shared__ float sStat[64 * 2];
    char* regA = smem;
    char* regB = smem + 36864;

    const int tid  = threadIdx.x;
    const int p0   = blockIdx.x * 64;
    const int irow = p0 >> 9;
    const int j0   = p0 & 511;
    const int wave = tid >> 6, lane = tid & 63, lq = lane >> 4, lr = lane & 15;

    // ---- phase 1: recompute sigmoid gate (fp32-grade, bf16-quantized inputs)
    u16* sLh = (u16*)regA; u16* sLl = sLh + 64*136;
    u16* sGh = (u16*)regB; u16* sGl = sGh + 64*136;
    ln_split(act, p0, lnw, lnb, sLh, sLl, tid);
    f32x4 gate[8];
    #pragma unroll 1
    for (int ch = 0; ch < 2; ++ch){
        __syncthreads();                         // publishes sL (ch=0) / frees sG (ch=1)
        load_w64s(glw + (size_t)(ch * 64) * CC, sGh, sGl, tid);
        __syncthreads();
        f32x4 res[4]; gemm64s(sLh, sLl, sGh, sGl, wave, lq, lr, res);
        #pragma unroll
        for (int t = 0; t < 4; ++t){
            const float gb = bq(glb[ch*64 + t*16 + lr]);
            f32x4 gv;
            #pragma unroll
            for (int r = 0; r < 4; ++r) gv[r] = sigm(res[t][r] + gb);
            gate[ch*4 + t] = gv;
        }
    }
    __syncthreads();                             // all sL/sG reads done

    // ---- phase 2: channel-LN of outT + output projection
    float* sRaw = (float*)regA;                  // [c][jj] fp32, stride 72
    {
        const int cc = tid >> 1, hf = tid & 1;
        if (OT16){
            const uint4* g4 = (const uint4*)((const u16*)outTv
                    + (size_t)cc * PP + (size_t)irow * SN + j0 + hf * 32);
            uint4 v[4];
            #pragma unroll
            for (int j = 0; j < 4; ++j) v[j] = g4[j];
            float* d = sRaw + cc * 72 + hf * 32;
            #pragma unroll
            for (int j = 0; j < 4; ++j){
                u16x8 hh = __builtin_bit_cast(u16x8, v[j]);
                #pragma unroll
                for (int e = 0; e < 8; ++e)
                    d[j*8+e] = (float)__builtin_bit_cast(_Float16, hh[e]);
            }
        } else {
            const float4* g4 = (const float4*)((const float*)outTv
                    + (size_t)cc * PP + (size_t)irow * SN + j0 + hf * 32);
            float4 v[8];
            #pragma unroll
            for (int j = 0; j < 8; ++j) v[j] = g4[j];
            float4* d = (float4*)(sRaw + cc * 72 + hf * 32);
            #pragma unroll
            for (int j = 0; j < 8; ++j) d[j] = v[j];
        }
    }
    __syncthreads();

    const int jj = tid & 63, cq = tid >> 6;
    {
        float s = 0.f, s2 = 0.f;
        #pragma unroll
        for (int t = 0; t < 32; ++t){
            float x = sRaw[(cq*32 + t) * 72 + jj];
            s += x; s2 += x * x;
        }
        sRed[jj*8 + cq] = s; sRed[jj*8 + 4 + cq] = s2;
    }
    __syncthreads();
    if (tid < 64){
        float s  = sRed[tid*8+0] + sRed[tid*8+1] + sRed[tid*8+2] + sRed[tid*8+3];
        float s2 = sRed[tid*8+4] + sRed[tid*8+5] + sRed[tid*8+6] + sRed[tid*8+7];
        float mean = s * (1.f / CC);
        sStat[tid*2+0] = mean;
        sStat[tid*2+1] = rsqrtf(s2 * (1.f / CC) - mean * mean + LNEPS);
    }
    __syncthreads();
    u16* sNh = (u16*)regB; u16* sNl = sNh + 64*136;   // sLn [jj][c] split
    {
        const float mean = sStat[jj*2+0], rstd = sStat[jj*2+1];
        #pragma unroll
        for (int t = 0; t < 32; ++t){
            const int ch = cq * 32 + t;
            const float x = (sRaw[ch * 72 + jj] - mean) * rstd * bq(cnw[ch]) + bq(cnb[ch]);
            split2(x, sNh[jj*136 + ch], sNl[jj*136 + ch]);
        }
    }
    u16* sOh = (u16*)regA; u16* sOl = sOh + 64*136;   // outp weights (overwrite sRaw)
    #pragma unroll 1
    for (int hf = 0; hf < 2; ++hf){
        __syncthreads();                         // sRaw reads done / prev weight reads done
        load_w64s(outpw + (size_t)(hf * 64) * CC, sOh, sOl, tid);
        __syncthreads();
        f32x4 res[4]; gemm64s(sNh, sNl, sOh, sOl, cq, lq, lr, res);
        #pragma unroll
        for (int t = 0; t < 4; ++t){
            const int col = hf*64 + t*16 + lr;
            const float ob = bq(outpb[col]);
            #pragma unroll
            for (int r = 0; r < 4; ++r){
                const int pos = p0 + cq*16 + lq*4 + r;
                io[(size_t)pos * CC + col] = (res[t][r] + ob) * gate[hf*4 + t][r];
            }
        }
    }
}

// ---------------------------------------------------------------------------
extern "C" void kernel_launch(void* const* d_in, const int* in_sizes, int n_in,
                              void* d_out, int out_size, void* d_ws, size_t ws_size,
                              hipStream_t stream)
{
    const float* act   = (const float*)d_in[0];
    const float* mask  = (const float*)d_in[1];
    const float* lnw   = (const float*)d_in[2];
    const float* lnb   = (const float*)d_in[3];
    const float* projw = (const float*)d_in[4];
    const float* projb = (const float*)d_in[5];
    const float* gatew = (const float*)d_in[6];
    const float* gateb = (const float*)d_in[7];
    const float* cnw   = (const float*)d_in[8];
    const float* cnb   = (const float*)d_in[9];
    const float* outpw = (const float*)d_in[10];
    const float* outpb = (const float*)d_in[11];
    const float* glw   = (const float*)d_in[12];
    const float* glb   = (const float*)d_in[13];

    // Workspace tiers (E = PP*CC elems = 64 MiB per fp16 plane):
    //   >=384MB: lp hi+lo | rp hi+lo | outT fp32   (best precision)
    //   >=320MB: lp hi+lo | rp hi+lo | outT fp16
    //   else   : lp hi+lo | rp hi    | outT fp16   (256MB, prior footprint)
    const size_t E    = (size_t)PP * CC;
    const size_t MB64 = E * sizeof(u16);
    u16* lph = (u16*)d_ws;
    u16* lpl = lph + E;
    u16* rph = lpl + E;

    const dim3 g2(4, 4, 128);
    if (ws_size >= 6 * MB64){
        u16*   rpl  = rph + E;
        float* outT = (float*)(rpl + E);
        k1_ln_proj<<<PP / 64, 256, 0, stream>>>(act, mask, lnw, lnb, projw, projb,
                                                gatew, gateb, lph, lpl, rph, rpl);
        k2_einsum<1,0><<<g2, 256, 0, stream>>>(lph, lpl, rph, rpl, outT);
        k3_out<0><<<PP / 64, 256, 0, stream>>>(act, outT, lnw, lnb, glw, glb,
                                               cnw, cnb, outpw, outpb, (float*)d_out);
    } else if (ws_size >= 5 * MB64){
        u16* rpl  = rph + E;
        u16* outT = rpl + E;
        k1_ln_proj<<<PP / 64, 256, 0, stream>>>(act, mask, lnw, lnb, projw, projb,
                                                gatew, gateb, lph, lpl, rph, rpl);
        k2_einsum<1,1><<<g2, 256, 0, stream>>>(lph, lpl, rph, rpl, outT);
        k3_out<1><<<PP / 64, 256, 0, stream>>>(act, outT, lnw, lnb, glw, glb,
                                               cnw, cnb, outpw, outpb, (float*)d_out);
    } else {
        u16* outT = rph + E;
        k1_ln_proj<<<PP / 64, 256, 0, stream>>>(act, mask, lnw, lnb, projw, projb,
                                                gatew, gateb, lph, lpl, rph, nullptr);
        k2_einsum<0,1><<<g2, 256, 0, stream>>>(lph, lpl, rph, nullptr, outT);
        k3_out<1><<<PP / 64, 256, 0, stream>>>(act, outT, lnw, lnb, glw, glb,
                                               cnw, cnb, outpw, outpb, (float*)d_out);
    }
}

// Round 4
// 885.845 us; speedup vs baseline: 1.0001x; 1.0001x over previous
//
#include <hip/hip_runtime.h>
#include <stdint.h>

typedef unsigned short u16;
typedef uint32_t u32;
typedef _Float16 f16x8 __attribute__((ext_vector_type(8)));
typedef u16 u16x8 __attribute__((ext_vector_type(8)));
typedef float f32x4 __attribute__((ext_vector_type(4)));

#define MFMA(a,b,c) __builtin_amdgcn_mfma_f32_16x16x32_f16((a),(b),(c),0,0,0)

constexpr int SN = 512;          // sequence N
constexpr int CC = 128;          // channels (CZ == CI)
constexpr int PP = SN * SN;      // positions
constexpr float LNEPS = 1e-5f;
constexpr float LO_SCALE = 2048.0f;     // 2^11: keeps residuals normal in fp16
constexpr float LO_INV   = 1.0f / 2048.0f;

// RNE bf16 quantization of an fp32 value (matches the np reference's input
// quantization — confirmed by an earlier first-validation pass).
__device__ __forceinline__ float bq(float f){
    u32 u = __builtin_bit_cast(u32, f);
    u += 0x7fffu + ((u >> 16) & 1u);
    return __builtin_bit_cast(float, u & 0xffff0000u);
}

// split fp32 -> (hi, lo) fp16 pair; x ~= hi + lo*2^-11, input precision ~2^-22
__device__ __forceinline__ void split2(float x, u16& h, u16& l){
    _Float16 a = (_Float16)x;
    _Float16 b = (_Float16)((x - (float)a) * LO_SCALE);
    h = __builtin_bit_cast(u16, a);
    l = __builtin_bit_cast(u16, b);
}
__device__ __forceinline__ u16 f2h(float f){
    _Float16 h = (_Float16)f;
    return __builtin_bit_cast(u16, h);
}
__device__ __forceinline__ f16x8 ld_frag(const u16* p){
    return __builtin_bit_cast(f16x8, *(const u16x8*)p);
}
__device__ __forceinline__ float sigm(float x){ return 1.0f / (1.0f + __expf(-x)); }

// Load 64 rows x 128 cols fp32 weights (row stride 128) -> bf16-quantized,
// split fp16 LDS, stride 136. Conversion in registers, stores batched uint4.
__device__ __forceinline__ void load_w64s(const float* __restrict__ src,
                                          u16* dh, u16* dl, int tid){
    const int r = tid >> 2, q = tid & 3;
    const float4* s4 = (const float4*)(src + (size_t)r * CC + q * 32);
    __align__(16) u16 hbuf[32], lbuf[32];
    #pragma unroll
    for (int j = 0; j < 8; ++j){
        float4 v = s4[j];
        split2(bq(v.x), hbuf[j*4+0], lbuf[j*4+0]);
        split2(bq(v.y), hbuf[j*4+1], lbuf[j*4+1]);
        split2(bq(v.z), hbuf[j*4+2], lbuf[j*4+2]);
        split2(bq(v.w), hbuf[j*4+3], lbuf[j*4+3]);
    }
    uint4* ph = (uint4*)(dh + r * 136 + q * 32);
    uint4* pl = (uint4*)(dl + r * 136 + q * 32);
    #pragma unroll
    for (int w = 0; w < 4; ++w){
        ph[w] = ((const uint4*)hbuf)[w];
        pl[w] = ((const uint4*)lbuf)[w];
    }
}

// LayerNorm of 64 positions of act (bf16-quantized) -> split fp16 LDS [pos][c],
// batched uint4 LDS stores.
__device__ __forceinline__ void ln_split(const float* __restrict__ act, int p0,
        const float* __restrict__ lnw, const float* __restrict__ lnb,
        u16* sLh, u16* sLl, int tid){
    const int pos = tid >> 2, q = tid & 3;
    const float4* a4 = (const float4*)(act + (size_t)(p0 + pos) * CC + q * 32);
    float4 av[8];
    float s = 0.f, s2 = 0.f;
    #pragma unroll
    for (int j = 0; j < 8; ++j){
        av[j] = a4[j];
        av[j].x = bq(av[j].x); av[j].y = bq(av[j].y);
        av[j].z = bq(av[j].z); av[j].w = bq(av[j].w);
        s  += av[j].x + av[j].y + av[j].z + av[j].w;
        s2 += av[j].x*av[j].x + av[j].y*av[j].y + av[j].z*av[j].z + av[j].w*av[j].w;
    }
    s  += __shfl_xor(s, 1);  s  += __shfl_xor(s, 2);
    s2 += __shfl_xor(s2, 1); s2 += __shfl_xor(s2, 2);
    const float mean = s * (1.f / CC);
    const float rstd = rsqrtf(s2 * (1.f / CC) - mean * mean + LNEPS);
    const float4* w4 = (const float4*)(lnw + q * 32);
    const float4* b4 = (const float4*)(lnb + q * 32);
    __align__(16) u16 hbuf[32], lbuf[32];
    #pragma unroll
    for (int j = 0; j < 8; ++j){
        float4 w = w4[j], b = b4[j];
        split2((av[j].x - mean) * rstd * bq(w.x) + bq(b.x), hbuf[j*4+0], lbuf[j*4+0]);
        split2((av[j].y - mean) * rstd * bq(w.y) + bq(b.y), hbuf[j*4+1], lbuf[j*4+1]);
        split2((av[j].z - mean) * rstd * bq(w.z) + bq(b.z), hbuf[j*4+2], lbuf[j*4+2]);
        split2((av[j].w - mean) * rstd * bq(w.w) + bq(b.w), hbuf[j*4+3], lbuf[j*4+3]);
    }
    uint4* ph = (uint4*)(sLh + pos * 136 + q * 32);
    uint4* pl = (uint4*)(sLl + pos * 136 + q * 32);
    #pragma unroll
    for (int w = 0; w < 4; ++w){
        ph[w] = ((const uint4*)hbuf)[w];
        pl[w] = ((const uint4*)lbuf)[w];
    }
}

// 64x64 split-precision GEMM tile: res[t] (t<4 col-tiles) for this wave's 16 rows
__device__ __forceinline__ void gemm64s(const u16* sLh, const u16* sLl,
        const u16* sWh, const u16* sWl, int wave, int lq, int lr, f32x4* res){
    f32x4 ah[4], al[4];
    #pragma unroll
    for (int t = 0; t < 4; ++t){ ah[t] = f32x4{0,0,0,0}; al[t] = f32x4{0,0,0,0}; }
    #pragma unroll
    for (int kk = 0; kk < 4; ++kk){
        const int ao = (wave*16 + lr) * 136 + kk * 32 + lq * 8;
        const f16x8 a_h = ld_frag(sLh + ao);
        const f16x8 a_l = ld_frag(sLl + ao);
        #pragma unroll
        for (int t = 0; t < 4; ++t){
            const int bo = (t*16 + lr) * 136 + kk * 32 + lq * 8;
            const f16x8 b_h = ld_frag(sWh + bo);
            const f16x8 b_l = ld_frag(sWl + bo);
            ah[t] = MFMA(a_h, b_h, ah[t]);
            al[t] = MFMA(a_h, b_l, al[t]);
            al[t] = MFMA(a_l, b_h, al[t]);
        }
    }
    #pragma unroll
    for (int t = 0; t < 4; ++t) res[t] = ah[t] + al[t] * LO_INV;
}

// ---------------------------------------------------------------------------
// Kernel 1: LN + gate/proj (split-precision MFMA) -> lp/rp SPLIT fp16 (hi+lo),
// (c,i,k) layout. rpl may be null (then rp is stored hi-only).
// ---------------------------------------------------------------------------
__global__ __launch_bounds__(256) void k1_ln_proj(
        const float* __restrict__ act,  const float* __restrict__ mask,
        const float* __restrict__ lnw,  const float* __restrict__ lnb,
        const float* __restrict__ projw,const float* __restrict__ projb,
        const float* __restrict__ gatew,const float* __restrict__ gateb,
        u16* __restrict__ lph, u16* __restrict__ lpl,
        u16* __restrict__ rph, u16* __restrict__ rpl)
{
    __shared__ __align__(16) u16 sLh[64*136], sLl[64*136];
    __shared__ __align__(16) u16 sW[2*64*136];   // weight hi|lo; reused as fp16 stage tile
    u16* sWh = sW;
    u16* sWl = sW + 64*136;

    const int tid  = threadIdx.x;
    const int p0   = blockIdx.x * 64;
    const int irow = p0 >> 9;
    const int k0   = p0 & 511;

    ln_split(act, p0, lnw, lnb, sLh, sLl, tid);

    const int wave = tid >> 6, lane = tid & 63, lq = lane >> 4, lr = lane & 15;
    const float4 mv = *(const float4*)(mask + p0 + wave*16 + lq*4);
    const float mr[4] = {bq(mv.x), bq(mv.y), bq(mv.z), bq(mv.w)};

    #pragma unroll 1
    for (int gh = 0; gh < 4; ++gh){
        const int g = gh >> 1, h = gh & 1;
        const int cb = g * 128 + h * 64;

        __syncthreads();                            // sT reads done; publishes sL on gh=0
        load_w64s(gatew + (size_t)cb * CC, sWh, sWl, tid);
        __syncthreads();
        f32x4 gres[4]; gemm64s(sLh, sLl, sWh, sWl, wave, lq, lr, gres);
        __syncthreads();                            // gate-weight reads done
        load_w64s(projw + (size_t)cb * CC, sWh, sWl, tid);
        __syncthreads();
        f32x4 pres[4]; gemm64s(sLh, sLl, sWh, sWl, wave, lq, lr, pres);
        __syncthreads();                            // proj-weight reads done

        u16* sTh = sW;                              // 64x72 fp16 hi [col][pos]
        u16* sTl = sW + 64*72;                      // 64x72 fp16 lo [col][pos]
        const int pos0 = wave * 16 + lq * 4;
        #pragma unroll
        for (int t = 0; t < 4; ++t){
            const int col = t * 16 + lr;
            const float qb = bq(gateb[cb + col]);
            const float pb = bq(projb[cb + col]);
            __align__(8) u16 th[4], tl[4];
            #pragma unroll
            for (int r = 0; r < 4; ++r){
                const float v = mr[r] * (pres[t][r] + pb) * sigm(gres[t][r] + qb);
                split2(v, th[r], tl[r]);
            }
            *(uint2*)(sTh + col * 72 + pos0) = *(const uint2*)th;
            *(uint2*)(sTl + col * 72 + pos0) = *(const uint2*)tl;
        }
        __syncthreads();

        {   // cooperative transposed write: dst[c][i][k] contiguous along k
            const int cl = tid >> 2, q = tid & 3;
            const size_t off = (size_t)(h*64 + cl) * PP + (size_t)irow * SN + k0 + q * 16;
            u16* dh = (g ? rph : lph) + off;
            const u16* sh = sTh + cl * 72 + q * 16;
            ((uint4*)dh)[0] = ((const uint4*)sh)[0];
            ((uint4*)dh)[1] = ((const uint4*)sh)[1];
            u16* lob = g ? rpl : lpl;
            if (lob){
                u16* dl = lob + off;
                const u16* sl = sTl + cl * 72 + q * 16;
                ((uint4*)dl)[0] = ((const uint4*)sl)[0];
                ((uint4*)dl)[1] = ((const uint4*)sl)[1];
            }
        }
    }
}

// ---------------------------------------------------------------------------
// Kernel 2: outT[c][i][j] = sum_k lp[c][i][k]*rp[c][j][k], split-precision
// fp16 MFMA (hi*hi + hi*lo + lo*hi; lo*lo ~2^-22 dropped), fp32 acc.
// RPS: rp has a lo plane. OT16: outT stored as fp16 instead of fp32.
// 1-D grid 2048 with bijective XCD-aware swizzle: 16 consecutive swz values
// (= one XCD's chunk) cover one channel's full 4x4 tile grid -> that XCD's L2
// holds the channel's lp/rp panels.
// ---------------------------------------------------------------------------
template<int RPS, int OT16>
__global__ __launch_bounds__(256) void k2_einsum(
        const u16* __restrict__ lph, const u16* __restrict__ lpl,
        const u16* __restrict__ rph, const u16* __restrict__ rpl,
        void* __restrict__ outTv)
{
    __shared__ __align__(16) u16 sAh[128*72], sAl[128*72], sBh[128*72];
    __shared__ __align__(16) u16 sBl[RPS ? 128*72 : 8];
    const int tid = threadIdx.x;
    const int bid = blockIdx.x;
    const int swz = (bid & 7) * 256 + (bid >> 3);   // XCD-contiguous chunks
    const int c   = swz >> 4;
    const int i0  = ((swz >> 2) & 3) * 128;
    const int j0  = (swz & 3) * 128;
    const size_t aoff = (size_t)c * PP + (size_t)i0 * SN;
    const size_t boff = (size_t)c * PP + (size_t)j0 * SN;
    const int wave = tid >> 6, lane = tid & 63, lq = lane >> 4, lr = lane & 15;
    const int wi = (wave & 1) * 64, wj = (wave >> 1) * 64;
    const int row = tid >> 1, half = tid & 1;
    const size_t goff = (size_t)row * SN + half * 32;

    f32x4 acch[4][4], accl[4][4];
    #pragma unroll
    for (int m = 0; m < 4; ++m)
        #pragma unroll
        for (int n = 0; n < 4; ++n){ acch[m][n] = f32x4{0,0,0,0}; accl[m][n] = f32x4{0,0,0,0}; }

    for (int k0 = 0; k0 < SN; k0 += 64){
        const uint4* gah = (const uint4*)(lph + aoff + goff + k0);
        const uint4* gal = (const uint4*)(lpl + aoff + goff + k0);
        const uint4* gbh = (const uint4*)(rph + boff + goff + k0);
        uint4 Ah0 = gah[0], Ah1 = gah[1], Ah2 = gah[2], Ah3 = gah[3];
        uint4 Al0 = gal[0], Al1 = gal[1], Al2 = gal[2], Al3 = gal[3];
        uint4 Bh0 = gbh[0], Bh1 = gbh[1], Bh2 = gbh[2], Bh3 = gbh[3];
        uint4 Bl0, Bl1, Bl2, Bl3;
        if (RPS){
            const uint4* gbl = (const uint4*)(rpl + boff + goff + k0);
            Bl0 = gbl[0]; Bl1 = gbl[1]; Bl2 = gbl[2]; Bl3 = gbl[3];
        }
        __syncthreads();                          // prev iter's frag reads done
        uint4* dah = (uint4*)(sAh + row * 72 + half * 32);
        uint4* dal = (uint4*)(sAl + row * 72 + half * 32);
        uint4* dbh = (uint4*)(sBh + row * 72 + half * 32);
        dah[0] = Ah0; dah[1] = Ah1; dah[2] = Ah2; dah[3] = Ah3;
        dal[0] = Al0; dal[1] = Al1; dal[2] = Al2; dal[3] = Al3;
        dbh[0] = Bh0; dbh[1] = Bh1; dbh[2] = Bh2; dbh[3] = Bh3;
        if (RPS){
            uint4* dbl = (uint4*)(sBl + row * 72 + half * 32);
            dbl[0] = Bl0; dbl[1] = Bl1; dbl[2] = Bl2; dbl[3] = Bl3;
        }
        __syncthreads();
        #pragma unroll
        for (int kk = 0; kk < 64; kk += 32){
            f16x8 ahf[4], alf[4], bhf[4], blf[RPS ? 4 : 1];
            #pragma unroll
            for (int m = 0; m < 4; ++m){
                const int ro = (wi + m*16 + lr) * 72 + kk + lq * 8;
                ahf[m] = ld_frag(sAh + ro);
                alf[m] = ld_frag(sAl + ro);
            }
            #pragma unroll
            for (int n = 0; n < 4; ++n){
                const int ro = (wj + n*16 + lr) * 72 + kk + lq * 8;
                bhf[n] = ld_frag(sBh + ro);
                if (RPS) blf[n] = ld_frag(sBl + ro);
            }
            #pragma unroll
            for (int m = 0; m < 4; ++m)
                #pragma unroll
                for (int n = 0; n < 4; ++n){
                    acch[m][n] = MFMA(ahf[m], bhf[n], acch[m][n]);
                    accl[m][n] = MFMA(alf[m], bhf[n], accl[m][n]);
                    if (RPS) accl[m][n] = MFMA(ahf[m], blf[n], accl[m][n]);
                }
        }
    }
    #pragma unroll
    for (int m = 0; m < 4; ++m){
        const int ir = i0 + wi + m * 16 + lq * 4;
        #pragma unroll
        for (int n = 0; n < 4; ++n){
            const int jc = j0 + wj + n * 16 + lr;
            #pragma unroll
            for (int r = 0; r < 4; ++r){
                const float v = acch[m][n][r] + accl[m][n][r] * LO_INV;
                if (OT16)
                    ((u16*)outTv)[(size_t)c * PP + (size_t)(ir + r) * SN + jc] = f2h(v);
                else
                    ((float*)outTv)[(size_t)c * PP + (size_t)(ir + r) * SN + jc] = v;
            }
        }
    }
}

// ---------------------------------------------------------------------------
// Kernel 3: gate = sigmoid(LN(act)@glw.T+glb) recomputed; channel-LN of outT;
// final = (LN_c(outT) @ outpw.T + outpb) * gate -> d_out (write-only, once).
// ---------------------------------------------------------------------------
template<int OT16>
__global__ __launch_bounds__(256) void k3_out(
        const float* __restrict__ act,  const void* __restrict__ outTv,
        const float* __restrict__ lnw,  const float* __restrict__ lnb,
        const float* __restrict__ glw,  const float* __restrict__ glb,
        const float* __restrict__ cnw,  const float* __restrict__ cnb,
        const float* __restrict__ outpw,const float* __restrict__ outpb,
        float* __restrict__ io)
{
    // regionA (36864 B): phase1 sL pair | phase2 sRaw | phase2 outp-weight pair
    // regionB (34816 B): phase1 gl-weight pair | phase2 sLn pair
    __shared__ __align__(16) char smem[36864 + 34816];
    __shared__ float sRed[64 * 8];
    __shared__ float sStat[64 * 2];
    char* regA = smem;
    char* regB = smem + 36864;

    const int tid  = threadIdx.x;
    const int p0   = blockIdx.x * 64;
    const int irow = p0 >> 9;
    const int j0   = p0 & 511;
    const int wave = tid >> 6, lane = tid & 63, lq = lane >> 4, lr = lane & 15;

    // ---- phase 1: recompute sigmoid gate (fp32-grade, bf16-quantized inputs)
    u16* sLh = (u16*)regA; u16* sLl = sLh + 64*136;
    u16* sGh = (u16*)regB; u16* sGl = sGh + 64*136;
    ln_split(act, p0, lnw, lnb, sLh, sLl, tid);
    f32x4 gate[8];
    #pragma unroll 1
    for (int ch = 0; ch < 2; ++ch){
        __syncthreads();                         // publishes sL (ch=0) / frees sG (ch=1)
        load_w64s(glw + (size_t)(ch * 64) * CC, sGh, sGl, tid);
        __syncthreads();
        f32x4 res[4]; gemm64s(sLh, sLl, sGh, sGl, wave, lq, lr, res);
        #pragma unroll
        for (int t = 0; t < 4; ++t){
            const float gb = bq(glb[ch*64 + t*16 + lr]);
            f32x4 gv;
            #pragma unroll
            for (int r = 0; r < 4; ++r) gv[r] = sigm(res[t][r] + gb);
            gate[ch*4 + t] = gv;
        }
    }
    __syncthreads();                             // all sL/sG reads done

    // ---- phase 2: channel-LN of outT + output projection
    float* sRaw = (float*)regA;                  // [c][jj] fp32, stride 72
    {
        const int cc = tid >> 1, hf = tid & 1;
        if (OT16){
            const uint4* g4 = (const uint4*)((const u16*)outTv
                    + (size_t)cc * PP + (size_t)irow * SN + j0 + hf * 32);
            uint4 v[4];
            #pragma unroll
            for (int j = 0; j < 4; ++j) v[j] = g4[j];
            float* d = sRaw + cc * 72 + hf * 32;
            #pragma unroll
            for (int j = 0; j < 4; ++j){
                u16x8 hh = __builtin_bit_cast(u16x8, v[j]);
                #pragma unroll
                for (int e = 0; e < 8; ++e)
                    d[j*8+e] = (float)__builtin_bit_cast(_Float16, hh[e]);
            }
        } else {
            const float4* g4 = (const float4*)((const float*)outTv
                    + (size_t)cc * PP + (size_t)irow * SN + j0 + hf * 32);
            float4 v[8];
            #pragma unroll
            for (int j = 0; j < 8; ++j) v[j] = g4[j];
            float4* d = (float4*)(sRaw + cc * 72 + hf * 32);
            #pragma unroll
            for (int j = 0; j < 8; ++j) d[j] = v[j];
        }
    }
    __syncthreads();

    const int jj = tid & 63, cq = tid >> 6;
    {
        float s = 0.f, s2 = 0.f;
        #pragma unroll
        for (int t = 0; t < 32; ++t){
            float x = sRaw[(cq*32 + t) * 72 + jj];
            s += x; s2 += x * x;
        }
        sRed[jj*8 + cq] = s; sRed[jj*8 + 4 + cq] = s2;
    }
    __syncthreads();
    if (tid < 64){
        float s  = sRed[tid*8+0] + sRed[tid*8+1] + sRed[tid*8+2] + sRed[tid*8+3];
        float s2 = sRed[tid*8+4] + sRed[tid*8+5] + sRed[tid*8+6] + sRed[tid*8+7];
        float mean = s * (1.f / CC);
        sStat[tid*2+0] = mean;
        sStat[tid*2+1] = rsqrtf(s2 * (1.f / CC) - mean * mean + LNEPS);
    }
    __syncthreads();
    u16* sNh = (u16*)regB; u16* sNl = sNh + 64*136;   // sLn [jj][c] split
    {
        const float mean = sStat[jj*2+0], rstd = sStat[jj*2+1];
        __align__(16) u16 nh[32], nl[32];
        #pragma unroll
        for (int t = 0; t < 32; ++t){
            const int ch = cq * 32 + t;
            const float x = (sRaw[ch * 72 + jj] - mean) * rstd * bq(cnw[ch]) + bq(cnb[ch]);
            split2(x, nh[t], nl[t]);
        }
        uint4* dh = (uint4*)(sNh + jj*136 + cq*32);
        uint4* dl = (uint4*)(sNl + jj*136 + cq*32);
        #pragma unroll
        for (int w = 0; w < 4; ++w){
            dh[w] = ((const uint4*)nh)[w];
            dl[w] = ((const uint4*)nl)[w];
        }
    }
    u16* sOh = (u16*)regA; u16* sOl = sOh + 64*136;   // outp weights (overwrite sRaw)
    #pragma unroll 1
    for (int hf = 0; hf < 2; ++hf){
        __syncthreads();                         // sRaw reads done / prev weight reads done
        load_w64s(outpw + (size_t)(hf * 64) * CC, sOh, sOl, tid);
        __syncthreads();
        f32x4 res[4]; gemm64s(sNh, sNl, sOh, sOl, cq, lq, lr, res);
        #pragma unroll
        for (int t = 0; t < 4; ++t){
            const int col = hf*64 + t*16 + lr;
            const float ob = bq(outpb[col]);
            #pragma unroll
            for (int r = 0; r < 4; ++r){
                const int pos = p0 + cq*16 + lq*4 + r;
                io[(size_t)pos * CC + col] = (res[t][r] + ob) * gate[hf*4 + t][r];
            }
        }
    }
}

// ---------------------------------------------------------------------------
extern "C" void kernel_launch(void* const* d_in, const int* in_sizes, int n_in,
                              void* d_out, int out_size, void* d_ws, size_t ws_size,
                              hipStream_t stream)
{
    const float* act   = (const float*)d_in[0];
    const float* mask  = (const float*)d_in[1];
    const float* lnw   = (const float*)d_in[2];
    const float* lnb   = (const float*)d_in[3];
    const float* projw = (const float*)d_in[4];
    const float* projb = (const float*)d_in[5];
    const float* gatew = (const float*)d_in[6];
    const float* gateb = (const float*)d_in[7];
    const float* cnw   = (const float*)d_in[8];
    const float* cnb   = (const float*)d_in[9];
    const float* outpw = (const float*)d_in[10];
    const float* outpb = (const float*)d_in[11];
    const float* glw   = (const float*)d_in[12];
    const float* glb   = (const float*)d_in[13];

    // Workspace tiers (E = PP*CC elems = 64 MiB per fp16 plane):
    //   >=384MB: lp hi+lo | rp hi+lo | outT fp32   (best precision)
    //   >=320MB: lp hi+lo | rp hi+lo | outT fp16
    //   else   : lp hi+lo | rp hi    | outT fp16   (256MB footprint)
    const size_t E    = (size_t)PP * CC;
    const size_t MB64 = E * sizeof(u16);
    u16* lph = (u16*)d_ws;
    u16* lpl = lph + E;
    u16* rph = lpl + E;

    if (ws_size >= 6 * MB64){
        u16*   rpl  = rph + E;
        float* outT = (float*)(rpl + E);
        k1_ln_proj<<<PP / 64, 256, 0, stream>>>(act, mask, lnw, lnb, projw, projb,
                                                gatew, gateb, lph, lpl, rph, rpl);
        k2_einsum<1,0><<<2048, 256, 0, stream>>>(lph, lpl, rph, rpl, outT);
        k3_out<0><<<PP / 64, 256, 0, stream>>>(act, outT, lnw, lnb, glw, glb,
                                               cnw, cnb, outpw, outpb, (float*)d_out);
    } else if (ws_size >= 5 * MB64){
        u16* rpl  = rph + E;
        u16* outT = rpl + E;
        k1_ln_proj<<<PP / 64, 256, 0, stream>>>(act, mask, lnw, lnb, projw, projb,
                                                gatew, gateb, lph, lpl, rph, rpl);
        k2_einsum<1,1><<<2048, 256, 0, stream>>>(lph, lpl, rph, rpl, outT);
        k3_out<1><<<PP / 64, 256, 0, stream>>>(act, outT, lnw, lnb, glw, glb,
                                               cnw, cnb, outpw, outpb, (float*)d_out);
    } else {
        u16* outT = rph + E;
        k1_ln_proj<<<PP / 64, 256, 0, stream>>>(act, mask, lnw, lnb, projw, projb,
                                                gatew, gateb, lph, lpl, rph, nullptr);
        k2_einsum<0,1><<<2048, 256, 0, stream>>>(lph, lpl, rph, nullptr, outT);
        k3_out<1><<<PP / 64, 256, 0, stream>>>(act, outT, lnw, lnb, glw, glb,
                                               cnw, cnb, outpw, outpb, (float*)d_out);
    }
}

// Round 6
// 751.565 us; speedup vs baseline: 1.1788x; 1.1787x over previous
//
#include <hip/hip_runtime.h>
#include <stdint.h>

typedef unsigned short u16;
typedef uint32_t u32;
typedef _Float16 f16x8 __attribute__((ext_vector_type(8)));
typedef u16 u16x8 __attribute__((ext_vector_type(8)));
typedef float f32x4 __attribute__((ext_vector_type(4)));

#define MFMA(a,b,c) __builtin_amdgcn_mfma_f32_16x16x32_f16((a),(b),(c),0,0,0)

constexpr int SN = 512;          // sequence N
constexpr int CC = 128;          // channels (CZ == CI)
constexpr int PP = SN * SN;      // positions
constexpr float LNEPS = 1e-5f;
constexpr float LO_SCALE = 2048.0f;     // 2^11: keeps residuals normal in fp16
constexpr float LO_INV   = 1.0f / 2048.0f;

// Pre-split weight plane offsets (elements) inside the d_ws head block.
constexpr int GATE_OFF = 0;             // 256x128
constexpr int PROJ_OFF = 32768;         // 256x128
constexpr int GL_OFF   = 65536;         // 128x128
constexpr int OUTP_OFF = 81920;         // 128x128
constexpr int WTOT     = 98304;

// RNE bf16 quantization of an fp32 value (matches the np reference's input
// quantization — confirmed by an earlier first-validation pass).
__device__ __forceinline__ float bq(float f){
    u32 u = __builtin_bit_cast(u32, f);
    u += 0x7fffu + ((u >> 16) & 1u);
    return __builtin_bit_cast(float, u & 0xffff0000u);
}

// split fp32 -> (hi, lo) fp16 pair; x ~= hi + lo*2^-11, input precision ~2^-22
__device__ __forceinline__ void split2(float x, u16& h, u16& l){
    _Float16 a = (_Float16)x;
    _Float16 b = (_Float16)((x - (float)a) * LO_SCALE);
    h = __builtin_bit_cast(u16, a);
    l = __builtin_bit_cast(u16, b);
}
__device__ __forceinline__ u16 f2h(float f){
    _Float16 h = (_Float16)f;
    return __builtin_bit_cast(u16, h);
}
__device__ __forceinline__ f16x8 ld_frag(const u16* p){
    return __builtin_bit_cast(f16x8, *(const u16x8*)p);
}
__device__ __forceinline__ float sigm(float x){ return 1.0f / (1.0f + __expf(-x)); }

// ---------------------------------------------------------------------------
// Kernel 0: one-time weight split fp32 -> bq -> (hi,lo) fp16 planes in d_ws.
// ---------------------------------------------------------------------------
__global__ __launch_bounds__(256) void k0_wsplit(
        const float* __restrict__ gatew, const float* __restrict__ projw,
        const float* __restrict__ glw,   const float* __restrict__ outpw,
        u16* __restrict__ wh, u16* __restrict__ wl)
{
    const int e = (blockIdx.x * 256 + threadIdx.x) * 4;
    const float* src; int o;
    if      (e < PROJ_OFF){ src = gatew; o = e; }
    else if (e < GL_OFF)  { src = projw; o = e - PROJ_OFF; }
    else if (e < OUTP_OFF){ src = glw;   o = e - GL_OFF; }
    else                  { src = outpw; o = e - OUTP_OFF; }
    const float4 v = *(const float4*)(src + o);
    __align__(8) u16 h[4], l[4];
    split2(bq(v.x), h[0], l[0]);
    split2(bq(v.y), h[1], l[1]);
    split2(bq(v.z), h[2], l[2]);
    split2(bq(v.w), h[3], l[3]);
    *(uint2*)(wh + e) = *(const uint2*)h;
    *(uint2*)(wl + e) = *(const uint2*)l;
}

// Stage 64x128 pre-split weights into LDS (stride 136): pure uint4 copy.
// Each thread owns 32 u16 per plane => FOUR uint4 copies per plane.
__device__ __forceinline__ void stage_pre(const u16* __restrict__ sh_,
        const u16* __restrict__ sl_, u16* dh, u16* dl, int tid){
    const int r = tid >> 2, q = tid & 3;
    const uint4* s1 = (const uint4*)(sh_ + r * CC + q * 32);
    const uint4* s2 = (const uint4*)(sl_ + r * CC + q * 32);
    uint4* d1 = (uint4*)(dh + r * 136 + q * 32);
    uint4* d2 = (uint4*)(dl + r * 136 + q * 32);
    #pragma unroll
    for (int w = 0; w < 4; ++w){
        d1[w] = s1[w];
        d2[w] = s2[w];
    }
}

// Legacy fallback: split fp32 weights in-kernel (conversion in regs, uint4 stores)
__device__ __forceinline__ void load_w64s(const float* __restrict__ src,
                                          u16* dh, u16* dl, int tid){
    const int r = tid >> 2, q = tid & 3;
    const float4* s4 = (const float4*)(src + (size_t)r * CC + q * 32);
    __align__(16) u16 hbuf[32], lbuf[32];
    #pragma unroll
    for (int j = 0; j < 8; ++j){
        float4 v = s4[j];
        split2(bq(v.x), hbuf[j*4+0], lbuf[j*4+0]);
        split2(bq(v.y), hbuf[j*4+1], lbuf[j*4+1]);
        split2(bq(v.z), hbuf[j*4+2], lbuf[j*4+2]);
        split2(bq(v.w), hbuf[j*4+3], lbuf[j*4+3]);
    }
    uint4* ph = (uint4*)(dh + r * 136 + q * 32);
    uint4* pl = (uint4*)(dl + r * 136 + q * 32);
    #pragma unroll
    for (int w = 0; w < 4; ++w){
        ph[w] = ((const uint4*)hbuf)[w];
        pl[w] = ((const uint4*)lbuf)[w];
    }
}

// Per-lane LN into MFMA A-fragments (registers, no LDS):
// lane (wave,lq,lr) produces row p0+wave*16+lr, cols kk*32+lq*8..+8 for kk<4.
// Identical per-element math to the LDS ln_split; row-sum order differs at ulp.
__device__ __forceinline__ void ln_frag(const float* __restrict__ act, int p0,
        const float* __restrict__ lnw, const float* __restrict__ lnb,
        int wave, int lq, int lr, f16x8* fh, f16x8* fl)
{
    const float* base = act + (size_t)(p0 + wave*16 + lr) * CC + lq * 8;
    float4 av[8];
    float s = 0.f, s2 = 0.f;
    #pragma unroll
    for (int kk = 0; kk < 4; ++kk){
        #pragma unroll
        for (int j = 0; j < 2; ++j){
            float4 v = *(const float4*)(base + kk*32 + j*4);
            v.x = bq(v.x); v.y = bq(v.y); v.z = bq(v.z); v.w = bq(v.w);
            av[kk*2+j] = v;
            s  += v.x + v.y + v.z + v.w;
            s2 += v.x*v.x + v.y*v.y + v.z*v.z + v.w*v.w;
        }
    }
    s  += __shfl_xor(s, 16);  s  += __shfl_xor(s, 32);
    s2 += __shfl_xor(s2, 16); s2 += __shfl_xor(s2, 32);
    const float mean = s * (1.f / CC);
    const float rstd = rsqrtf(s2 * (1.f / CC) - mean * mean + LNEPS);
    #pragma unroll
    for (int kk = 0; kk < 4; ++kk){
        __align__(16) u16 h[8], l[8];
        #pragma unroll
        for (int j = 0; j < 2; ++j){
            const float4 v = av[kk*2+j];
            const float4 w = *(const float4*)(lnw + lq*8 + kk*32 + j*4);
            const float4 b = *(const float4*)(lnb + lq*8 + kk*32 + j*4);
            split2((v.x-mean)*rstd*bq(w.x)+bq(b.x), h[j*4+0], l[j*4+0]);
            split2((v.y-mean)*rstd*bq(w.y)+bq(b.y), h[j*4+1], l[j*4+1]);
            split2((v.z-mean)*rstd*bq(w.z)+bq(b.z), h[j*4+2], l[j*4+2]);
            split2((v.w-mean)*rstd*bq(w.w)+bq(b.w), h[j*4+3], l[j*4+3]);
        }
        fh[kk] = __builtin_bit_cast(f16x8, *(const u16x8*)h);
        fl[kk] = __builtin_bit_cast(f16x8, *(const u16x8*)l);
    }
}

// 64x64 split-precision GEMM tile: A-frags from regs, B from LDS (stride 136).
__device__ __forceinline__ void gemm64r(const f16x8* fh, const f16x8* fl,
        const u16* __restrict__ sWh, const u16* __restrict__ sWl,
        int lq, int lr, f32x4* res)
{
    f32x4 ah[4], al[4];
    #pragma unroll
    for (int t = 0; t < 4; ++t){ ah[t] = f32x4{0,0,0,0}; al[t] = f32x4{0,0,0,0}; }
    #pragma unroll
    for (int kk = 0; kk < 4; ++kk){
        const f16x8 a_h = fh[kk], a_l = fl[kk];
        #pragma unroll
        for (int t = 0; t < 4; ++t){
            const int bo = (t*16 + lr) * 136 + kk * 32 + lq * 8;
            const f16x8 b_h = ld_frag(sWh + bo);
            const f16x8 b_l = ld_frag(sWl + bo);
            ah[t] = MFMA(a_h, b_h, ah[t]);
            al[t] = MFMA(a_h, b_l, al[t]);
            al[t] = MFMA(a_l, b_h, al[t]);
        }
    }
    #pragma unroll
    for (int t = 0; t < 4; ++t) res[t] = ah[t] + al[t] * LO_INV;
}

// ---------------------------------------------------------------------------
// Kernel 1: LN (in-reg) + gate/proj (split MFMA) -> lp/rp split fp16, (c,i,k).
// LDS: weights 34816 + transpose tile 18432 = 53248 B -> 3 blocks/CU.
// ---------------------------------------------------------------------------
__global__ __launch_bounds__(256, 3) void k1_ln_proj(
        const float* __restrict__ act,  const float* __restrict__ mask,
        const float* __restrict__ lnw,  const float* __restrict__ lnb,
        const float* __restrict__ projw,const float* __restrict__ projb,
        const float* __restrict__ gatew,const float* __restrict__ gateb,
        const u16* __restrict__ wph,    const u16* __restrict__ wpl,
        u16* __restrict__ lph, u16* __restrict__ lpl,
        u16* __restrict__ rph, u16* __restrict__ rpl)
{
    __shared__ __align__(16) u16 sW[2*64*136];   // weight hi|lo
    __shared__ __align__(16) u16 sT[2*64*72];    // transpose hi|lo
    u16* sWh = sW;  u16* sWl = sW + 64*136;
    u16* sTh = sT;  u16* sTl = sT + 64*72;

    const int tid  = threadIdx.x;
    const int p0   = blockIdx.x * 64;
    const int irow = p0 >> 9;
    const int k0   = p0 & 511;
    const int wave = tid >> 6, lane = tid & 63, lq = lane >> 4, lr = lane & 15;

    f16x8 fh[4], fl[4];
    ln_frag(act, p0, lnw, lnb, wave, lq, lr, fh, fl);

    const float4 mv = *(const float4*)(mask + p0 + wave*16 + lq*4);
    const float mr[4] = {bq(mv.x), bq(mv.y), bq(mv.z), bq(mv.w)};

    #pragma unroll 1
    for (int gh = 0; gh < 4; ++gh){
        const int g = gh >> 1, h = gh & 1;
        const int cb = g * 128 + h * 64;

        __syncthreads();                 // prev sT global-write reads + sW reads done
        if (wph) stage_pre(wph + GATE_OFF + cb*CC, wpl + GATE_OFF + cb*CC, sWh, sWl, tid);
        else     load_w64s(gatew + (size_t)cb * CC, sWh, sWl, tid);
        __syncthreads();
        f32x4 gres[4]; gemm64r(fh, fl, sWh, sWl, lq, lr, gres);
        __syncthreads();                 // gate-weight reads done
        if (wph) stage_pre(wph + PROJ_OFF + cb*CC, wpl + PROJ_OFF + cb*CC, sWh, sWl, tid);
        else     load_w64s(projw + (size_t)cb * CC, sWh, sWl, tid);
        __syncthreads();
        f32x4 pres[4]; gemm64r(fh, fl, sWh, sWl, lq, lr, pres);

        const int pos0 = wave * 16 + lq * 4;
        #pragma unroll
        for (int t = 0; t < 4; ++t){
            const int col = t * 16 + lr;
            const float qb = bq(gateb[cb + col]);
            const float pb = bq(projb[cb + col]);
            __align__(8) u16 th[4], tl[4];
            #pragma unroll
            for (int r = 0; r < 4; ++r){
                const float v = mr[r] * (pres[t][r] + pb) * sigm(gres[t][r] + qb);
                split2(v, th[r], tl[r]);
            }
            *(uint2*)(sTh + col * 72 + pos0) = *(const uint2*)th;
            *(uint2*)(sTl + col * 72 + pos0) = *(const uint2*)tl;
        }
        __syncthreads();                 // sT written + proj-weight reads done

        {   // cooperative transposed write: dst[c][i][k] contiguous along k
            const int cl = tid >> 2, q = tid & 3;
            const size_t off = (size_t)(h*64 + cl) * PP + (size_t)irow * SN + k0 + q * 16;
            u16* dh = (g ? rph : lph) + off;
            const u16* shp = sTh + cl * 72 + q * 16;
            ((uint4*)dh)[0] = ((const uint4*)shp)[0];
            ((uint4*)dh)[1] = ((const uint4*)shp)[1];
            u16* lob = g ? rpl : lpl;
            if (lob){
                u16* dl = lob + off;
                const u16* slp = sTl + cl * 72 + q * 16;
                ((uint4*)dl)[0] = ((const uint4*)slp)[0];
                ((uint4*)dl)[1] = ((const uint4*)slp)[1];
            }
        }
    }
}

// ---------------------------------------------------------------------------
// Kernel 2: outT[c][i][j] = sum_k lp[c][i][k]*rp[c][j][k], split-precision
// fp16 MFMA (hi*hi + hi*lo + lo*hi), fp32 acc. Unchanged (green round 4).
// ---------------------------------------------------------------------------
template<int RPS, int OT16>
__global__ __launch_bounds__(256) void k2_einsum(
        const u16* __restrict__ lph, const u16* __restrict__ lpl,
        const u16* __restrict__ rph, const u16* __restrict__ rpl,
        void* __restrict__ outTv)
{
    __shared__ __align__(16) u16 sAh[128*72], sAl[128*72], sBh[128*72];
    __shared__ __align__(16) u16 sBl[RPS ? 128*72 : 8];
    const int tid = threadIdx.x;
    const int bid = blockIdx.x;
    const int swz = (bid & 7) * 256 + (bid >> 3);   // XCD-contiguous chunks
    const int c   = swz >> 4;
    const int i0  = ((swz >> 2) & 3) * 128;
    const int j0  = (swz & 3) * 128;
    const size_t aoff = (size_t)c * PP + (size_t)i0 * SN;
    const size_t boff = (size_t)c * PP + (size_t)j0 * SN;
    const int wave = tid >> 6, lane = tid & 63, lq = lane >> 4, lr = lane & 15;
    const int wi = (wave & 1) * 64, wj = (wave >> 1) * 64;
    const int row = tid >> 1, half = tid & 1;
    const size_t goff = (size_t)row * SN + half * 32;

    f32x4 acch[4][4], accl[4][4];
    #pragma unroll
    for (int m = 0; m < 4; ++m)
        #pragma unroll
        for (int n = 0; n < 4; ++n){ acch[m][n] = f32x4{0,0,0,0}; accl[m][n] = f32x4{0,0,0,0}; }

    for (int k0 = 0; k0 < SN; k0 += 64){
        const uint4* gah = (const uint4*)(lph + aoff + goff + k0);
        const uint4* gal = (const uint4*)(lpl + aoff + goff + k0);
        const uint4* gbh = (const uint4*)(rph + boff + goff + k0);
        uint4 Ah0 = gah[0], Ah1 = gah[1], Ah2 = gah[2], Ah3 = gah[3];
        uint4 Al0 = gal[0], Al1 = gal[1], Al2 = gal[2], Al3 = gal[3];
        uint4 Bh0 = gbh[0], Bh1 = gbh[1], Bh2 = gbh[2], Bh3 = gbh[3];
        uint4 Bl0, Bl1, Bl2, Bl3;
        if (RPS){
            const uint4* gbl = (const uint4*)(rpl + boff + goff + k0);
            Bl0 = gbl[0]; Bl1 = gbl[1]; Bl2 = gbl[2]; Bl3 = gbl[3];
        }
        __syncthreads();                          // prev iter's frag reads done
        uint4* dah = (uint4*)(sAh + row * 72 + half * 32);
        uint4* dal = (uint4*)(sAl + row * 72 + half * 32);
        uint4* dbh = (uint4*)(sBh + row * 72 + half * 32);
        dah[0] = Ah0; dah[1] = Ah1; dah[2] = Ah2; dah[3] = Ah3;
        dal[0] = Al0; dal[1] = Al1; dal[2] = Al2; dal[3] = Al3;
        dbh[0] = Bh0; dbh[1] = Bh1; dbh[2] = Bh2; dbh[3] = Bh3;
        if (RPS){
            uint4* dbl = (uint4*)(sBl + row * 72 + half * 32);
            dbl[0] = Bl0; dbl[1] = Bl1; dbl[2] = Bl2; dbl[3] = Bl3;
        }
        __syncthreads();
        #pragma unroll
        for (int kk = 0; kk < 64; kk += 32){
            f16x8 ahf[4], alf[4], bhf[4], blf[RPS ? 4 : 1];
            #pragma unroll
            for (int m = 0; m < 4; ++m){
                const int ro = (wi + m*16 + lr) * 72 + kk + lq * 8;
                ahf[m] = ld_frag(sAh + ro);
                alf[m] = ld_frag(sAl + ro);
            }
            #pragma unroll
            for (int n = 0; n < 4; ++n){
                const int ro = (wj + n*16 + lr) * 72 + kk + lq * 8;
                bhf[n] = ld_frag(sBh + ro);
                if (RPS) blf[n] = ld_frag(sBl + ro);
            }
            #pragma unroll
            for (int m = 0; m < 4; ++m)
                #pragma unroll
                for (int n = 0; n < 4; ++n){
                    acch[m][n] = MFMA(ahf[m], bhf[n], acch[m][n]);
                    accl[m][n] = MFMA(alf[m], bhf[n], accl[m][n]);
                    if (RPS) accl[m][n] = MFMA(ahf[m], blf[n], accl[m][n]);
                }
        }
    }
    #pragma unroll
    for (int m = 0; m < 4; ++m){
        const int ir = i0 + wi + m * 16 + lq * 4;
        #pragma unroll
        for (int n = 0; n < 4; ++n){
            const int jc = j0 + wj + n * 16 + lr;
            #pragma unroll
            for (int r = 0; r < 4; ++r){
                const float v = acch[m][n][r] + accl[m][n][r] * LO_INV;
                if (OT16)
                    ((u16*)outTv)[(size_t)c * PP + (size_t)(ir + r) * SN + jc] = f2h(v);
                else
                    ((float*)outTv)[(size_t)c * PP + (size_t)(ir + r) * SN + jc] = v;
            }
        }
    }
}

// ---------------------------------------------------------------------------
// Kernel 3: gate recompute (in-reg LN + gl gemm); channel-LN of outT with
// N-fragments built per-lane in registers; output projection; final gate.
// LDS: one 36864 B region (sG | sRaw | sO) + stats -> 3 blocks/CU.
// ---------------------------------------------------------------------------
template<int OT16>
__global__ __launch_bounds__(256, 3) void k3_out(
        const float* __restrict__ act,  const void* __restrict__ outTv,
        const float* __restrict__ lnw,  const float* __restrict__ lnb,
        const float* __restrict__ glw,  const float* __restrict__ glb,
        const float* __restrict__ cnw,  const float* __restrict__ cnb,
        const float* __restrict__ outpw,const float* __restrict__ outpb,
        const u16* __restrict__ wph,    const u16* __restrict__ wpl,
        float* __restrict__ io)
{
    __shared__ __align__(16) char smem[36864];   // sG(34816) | sRaw(36864) | sO(34816)
    __shared__ float sRed[64 * 8];
    __shared__ float sStat[64 * 2];

    const int tid  = threadIdx.x;
    const int p0   = blockIdx.x * 64;
    const int irow = p0 >> 9;
    const int j0   = p0 & 511;
    const int wave = tid >> 6, lane = tid & 63, lq = lane >> 4, lr = lane & 15;

    // ---- phase 1: gate = sigmoid(LN(act)@glw.T+glb), LN in registers
    u16* sGh = (u16*)smem; u16* sGl = sGh + 64*136;
    f16x8 fh[4], fl[4];
    ln_frag(act, p0, lnw, lnb, wave, lq, lr, fh, fl);
    f32x4 gate[8];
    #pragma unroll 1
    for (int ch = 0; ch < 2; ++ch){
        __syncthreads();                         // prev gemm's weight reads done
        if (wph) stage_pre(wph + GL_OFF + ch*64*CC, wpl + GL_OFF + ch*64*CC, sGh, sGl, tid);
        else     load_w64s(glw + (size_t)(ch * 64) * CC, sGh, sGl, tid);
        __syncthreads();
        f32x4 res[4]; gemm64r(fh, fl, sGh, sGl, lq, lr, res);
        #pragma unroll
        for (int t = 0; t < 4; ++t){
            const float gb = bq(glb[ch*64 + t*16 + lr]);
            f32x4 gv;
            #pragma unroll
            for (int r = 0; r < 4; ++r) gv[r] = sigm(res[t][r] + gb);
            gate[ch*4 + t] = gv;
        }
    }
    __syncthreads();                             // gl weight reads done; smem free

    // ---- phase 2: channel-LN of outT + output projection
    float* sRaw = (float*)smem;                  // [c][jj] fp32, stride 72
    {
        const int cc = tid >> 1, hfj = tid & 1;
        if (OT16){
            const uint4* g4 = (const uint4*)((const u16*)outTv
                    + (size_t)cc * PP + (size_t)irow * SN + j0 + hfj * 32);
            uint4 v[4];
            #pragma unroll
            for (int j = 0; j < 4; ++j) v[j] = g4[j];
            float* d = sRaw + cc * 72 + hfj * 32;
            #pragma unroll
            for (int j = 0; j < 4; ++j){
                u16x8 hh = __builtin_bit_cast(u16x8, v[j]);
                #pragma unroll
                for (int e = 0; e < 8; ++e)
                    d[j*8+e] = (float)__builtin_bit_cast(_Float16, hh[e]);
            }
        } else {
            const float4* g4 = (const float4*)((const float*)outTv
                    + (size_t)cc * PP + (size_t)irow * SN + j0 + hfj * 32);
            float4 v[8];
            #pragma unroll
            for (int j = 0; j < 8; ++j) v[j] = g4[j];
            float4* d = (float4*)(sRaw + cc * 72 + hfj * 32);
            #pragma unroll
            for (int j = 0; j < 8; ++j) d[j] = v[j];
        }
    }
    __syncthreads();

    const int jj = tid & 63;
    {
        float s = 0.f, s2 = 0.f;
        #pragma unroll
        for (int t = 0; t < 32; ++t){
            float x = sRaw[(wave*32 + t) * 72 + jj];
            s += x; s2 += x * x;
        }
        sRed[jj*8 + wave] = s; sRed[jj*8 + 4 + wave] = s2;
    }
    __syncthreads();
    if (tid < 64){
        float s  = sRed[tid*8+0] + sRed[tid*8+1] + sRed[tid*8+2] + sRed[tid*8+3];
        float s2 = sRed[tid*8+4] + sRed[tid*8+5] + sRed[tid*8+6] + sRed[tid*8+7];
        float mean = s * (1.f / CC);
        sStat[tid*2+0] = mean;
        sStat[tid*2+1] = rsqrtf(s2 * (1.f / CC) - mean * mean + LNEPS);
    }
    __syncthreads();

    // N-fragments in registers: lane handles row wave*16+lr, cols kk*32+lq*8..+8
    f16x8 nh[4], nl2[4];
    {
        const int row = wave * 16 + lr;
        const float mean = sStat[row*2+0], rstd = sStat[row*2+1];
        #pragma unroll
        for (int kk = 0; kk < 4; ++kk){
            __align__(16) u16 h[8], l[8];
            #pragma unroll
            for (int j = 0; j < 2; ++j){
                const int ch = kk*32 + lq*8 + j*4;
                const float4 w = *(const float4*)(cnw + ch);
                const float4 b = *(const float4*)(cnb + ch);
                split2((sRaw[(ch+0)*72+row]-mean)*rstd*bq(w.x)+bq(b.x), h[j*4+0], l[j*4+0]);
                split2((sRaw[(ch+1)*72+row]-mean)*rstd*bq(w.y)+bq(b.y), h[j*4+1], l[j*4+1]);
                split2((sRaw[(ch+2)*72+row]-mean)*rstd*bq(w.z)+bq(b.z), h[j*4+2], l[j*4+2]);
                split2((sRaw[(ch+3)*72+row]-mean)*rstd*bq(w.w)+bq(b.w), h[j*4+3], l[j*4+3]);
            }
            nh[kk]  = __builtin_bit_cast(f16x8, *(const u16x8*)h);
            nl2[kk] = __builtin_bit_cast(f16x8, *(const u16x8*)l);
        }
    }
    __syncthreads();                             // sRaw reads done; region -> sO

    u16* sOh = (u16*)smem; u16* sOl = sOh + 64*136;
    #pragma unroll 1
    for (int hf = 0; hf < 2; ++hf){
        if (wph) stage_pre(wph + OUTP_OFF + hf*64*CC, wpl + OUTP_OFF + hf*64*CC, sOh, sOl, tid);
        else     load_w64s(outpw + (size_t)(hf * 64) * CC, sOh, sOl, tid);
        __syncthreads();
        f32x4 res[4]; gemm64r(nh, nl2, sOh, sOl, lq, lr, res);
        #pragma unroll
        for (int t = 0; t < 4; ++t){
            const int col = hf*64 + t*16 + lr;
            const float ob = bq(outpb[col]);
            #pragma unroll
            for (int r = 0; r < 4; ++r){
                const int pos = p0 + wave*16 + lq*4 + r;
                io[(size_t)pos * CC + col] = (res[t][r] + ob) * gate[hf*4 + t][r];
            }
        }
        __syncthreads();                         // weight reads done before restage
    }
}

// ---------------------------------------------------------------------------
extern "C" void kernel_launch(void* const* d_in, const int* in_sizes, int n_in,
                              void* d_out, int out_size, void* d_ws, size_t ws_size,
                              hipStream_t stream)
{
    const float* act   = (const float*)d_in[0];
    const float* mask  = (const float*)d_in[1];
    const float* lnw   = (const float*)d_in[2];
    const float* lnb   = (const float*)d_in[3];
    const float* projw = (const float*)d_in[4];
    const float* projb = (const float*)d_in[5];
    const float* gatew = (const float*)d_in[6];
    const float* gateb = (const float*)d_in[7];
    const float* cnw   = (const float*)d_in[8];
    const float* cnb   = (const float*)d_in[9];
    const float* outpw = (const float*)d_in[10];
    const float* outpb = (const float*)d_in[11];
    const float* glw   = (const float*)d_in[12];
    const float* glb   = (const float*)d_in[13];

    const size_t E    = (size_t)PP * CC;
    const size_t MB64 = E * sizeof(u16);
    const size_t WB   = (size_t)WTOT * 2 * sizeof(u16);   // 393216 B

    // Pre-split weights at the head of d_ws if they fit alongside >= tier-3.
    u16* wph = nullptr; u16* wpl = nullptr;
    u16* base = (u16*)d_ws; size_t avail = ws_size;
    if (ws_size >= 4 * MB64 + WB){
        wph = (u16*)d_ws; wpl = wph + WTOT; base = wpl + WTOT; avail = ws_size - WB;
    }
    u16* lph = base;
    u16* lpl = lph + E;
    u16* rph = lpl + E;

    if (wph) k0_wsplit<<<WTOT / 1024, 256, 0, stream>>>(gatew, projw, glw, outpw, wph, wpl);

    if (avail >= 6 * MB64){
        u16*   rpl  = rph + E;
        float* outT = (float*)(rpl + E);
        k1_ln_proj<<<PP / 64, 256, 0, stream>>>(act, mask, lnw, lnb, projw, projb,
                                                gatew, gateb, wph, wpl, lph, lpl, rph, rpl);
        k2_einsum<1,0><<<2048, 256, 0, stream>>>(lph, lpl, rph, rpl, outT);
        k3_out<0><<<PP / 64, 256, 0, stream>>>(act, outT, lnw, lnb, glw, glb,
                                               cnw, cnb, outpw, outpb, wph, wpl,
                                               (float*)d_out);
    } else if (avail >= 5 * MB64){
        u16* rpl  = rph + E;
        u16* outT = rpl + E;
        k1_ln_proj<<<PP / 64, 256, 0, stream>>>(act, mask, lnw, lnb, projw, projb,
                                                gatew, gateb, wph, wpl, lph, lpl, rph, rpl);
        k2_einsum<1,1><<<2048, 256, 0, stream>>>(lph, lpl, rph, rpl, outT);
        k3_out<1><<<PP / 64, 256, 0, stream>>>(act, outT, lnw, lnb, glw, glb,
                                               cnw, cnb, outpw, outpb, wph, wpl,
                                               (float*)d_out);
    } else {
        u16* outT = rph + E;
        k1_ln_proj<<<PP / 64, 256, 0, stream>>>(act, mask, lnw, lnb, projw, projb,
                                                gatew, gateb, wph, wpl, lph, lpl, rph, nullptr);
        k2_einsum<0,1><<<2048, 256, 0, stream>>>(lph, lpl, rph, nullptr, outT);
        k3_out<1><<<PP / 64, 256, 0, stream>>>(act, outT, lnw, lnb, glw, glb,
                                               cnw, cnb, outpw, outpb, wph, wpl,
                                               (float*)d_out);
    }
}